// Round 8
// baseline (2515.054 us; speedup 1.0000x reference)
//
#include <hip/hip_runtime.h>
#include <hip/hip_bf16.h>
#include <math.h>

typedef __hip_bfloat16 bf16;
typedef __attribute__((ext_vector_type(8))) short short8;
typedef __attribute__((ext_vector_type(4))) float f32x4;

#define D_    512
#define H_    4
#define DH_   128
#define L_    4
#define FF_   512
#define B_    64
#define NH_   6
#define S_    256
#define T_    64
#define IMG_  2048
#define NTMAX 24576
#define QCHUNK ((size_t)NTMAX * D_)   // element stride between q,k,v buffers

__device__ __forceinline__ float toF(bf16 v)  { return __bfloat162float(v); }
__device__ __forceinline__ float toF(float v) { return v; }
__device__ __forceinline__ void storeF(bf16* p, float v)  { *p = __float2bfloat16(v); }
__device__ __forceinline__ void storeF(float* p, float v) { *p = v; }

// round-to-nearest-even f32 -> bf16 bits
__device__ __forceinline__ unsigned short f2b(float f) {
    unsigned u = __float_as_uint(f);
    unsigned r = (u + 0x7fffu + ((u >> 16) & 1u)) >> 16;
    return (unsigned short)r;
}

// ---- weight transpose + cast: src[R][C] fp32 -> dst[C][R] bf16, z = layer.
// src layer stride R*Cc, dst layer stride dstride (elements).
__global__ void transpose_cast(const float* __restrict__ src, bf16* __restrict__ dst,
                               int R, int Cc, size_t dstride) {
    __shared__ float t[32][33];
    src += (size_t)blockIdx.z * R * Cc;
    dst += (size_t)blockIdx.z * dstride;
    int c0 = blockIdx.x * 32, r0 = blockIdx.y * 32;
    int tx = threadIdx.x & 31, ty = threadIdx.x >> 5;  // 256 thr: ty 0..7
    for (int i = ty; i < 32; i += 8) t[i][tx] = src[(size_t)(r0 + i) * Cc + c0 + tx];
    __syncthreads();
    for (int i = ty; i < 32; i += 8)
        dst[(size_t)(c0 + i) * R + r0 + tx] = __float2bfloat16(t[tx][i]);
}

// ---- flat f32 -> bf16 cast ----
__global__ void cast_bf16(const float* __restrict__ src, bf16* __restrict__ dst, int n) {
    int i = blockIdx.x * blockDim.x + threadIdx.x;
    if (i < n) dst[i] = __float2bfloat16(src[i]);
}

// ---- gather qkv bias: o[l][0:512]=bq[l], [512:1024]=bk[l], [1024:1536]=bv[l] ----
__global__ void gather_qkv_bias(const float* __restrict__ bq, const float* __restrict__ bk,
                                const float* __restrict__ bv, float* __restrict__ o) {
    int idx = blockIdx.x * blockDim.x + threadIdx.x;  // L_*1536 = 6144
    if (idx >= L_ * 1536) return;
    int l = idx / 1536, j = idx - l * 1536;
    int which = j >> 9, rem = j & 511;
    const float* s = (which == 0) ? bq : (which == 1) ? bk : bv;
    o[idx] = s[l * 512 + rem];
}

// ---- embedding + positional encoding: bf16 out ----
__global__ void embed_kernel(const int* __restrict__ tokens,
                             const float* __restrict__ emb,
                             bf16* __restrict__ x16,
                             int Tt, int total) {
    int idx = blockIdx.x * blockDim.x + threadIdx.x;
    if (idx >= total) return;
    int d   = idx & (D_ - 1);
    int row = idx >> 9;
    int t   = row % Tt;
    int tok = tokens[row];
    int i   = d >> 1;
    float ex  = -(float)(2 * i) * (9.210340371976184f / 512.0f);
    float dv  = expf(ex);
    float ang = (float)t * dv;
    float pe  = (d & 1) ? cosf(ang) : sinf(ang);
    x16[idx] = __float2bfloat16(emb[(size_t)tok * D_ + d] + pe);
}

// ---- MFMA bf16 GEMM: C[M,N] = A[M,K] @ B[K,N] + bias, B given transposed Bt[N][K]
// 128x128 tile, BK=64, 4 waves each computing 64x64 via 4x4 MFMAs 16x16x32.
// lt < 0 : row-major out, optional addC (in-place += on C) and relu.
// lt >= 0, vt=2 (fused qkv, N=1536): which=gc>>9 selects chunk C + which*QCHUNK;
//   which 0,1 (q,k): head-major out[((mq*H+h)*Tt + qi)*128 + dh], Tt=1<<lt
//   which 2   (v) : transposed  out[((mq*H+h)*128 + dh)*Tt + qi]
// XCD swizzle: when gridDim.y % 8 == 0, remap blocks so consecutive ids (same XCD
// mod 8) share a row-panel for A L2 locality.
template <typename CT>
__global__ __launch_bounds__(256) void gemm_mfma(
    const bf16* __restrict__ A, const bf16* __restrict__ Bt,
    const float* __restrict__ bias, CT* __restrict__ C,
    int M, int N, int K, int lt, int relu, int addC, int vt) {
    __shared__ short As[128][72];   // +8 shorts pad: 16B-aligned rows, 2-way-max banks
    __shared__ short Bs[128][72];
    int tid  = threadIdx.x;
    int wave = tid >> 6, lane = tid & 63, lr = lane & 15, quad = lane >> 4;
    int wr = (wave >> 1) * 64, wc = (wave & 1) * 64;
    int bx = blockIdx.x, by = blockIdx.y;
    if ((gridDim.y & 7) == 0) {
        int id = by * gridDim.x + bx;
        int xcd = id & 7, slot = id >> 3;
        by = xcd + 8 * (slot / gridDim.x);
        bx = slot % gridDim.x;
    }
    int row0 = by * 128, col0 = bx * 128;
    f32x4 acc[4][4];
    f32x4 zz = {0.f, 0.f, 0.f, 0.f};
#pragma unroll
    for (int mi = 0; mi < 4; ++mi)
#pragma unroll
        for (int ni = 0; ni < 4; ++ni) acc[mi][ni] = zz;

    for (int kt = 0; kt < K; kt += 64) {
        // stage 128x64 bf16 tiles: 1024 chunks of 8 shorts (16B), 4 per thread
#pragma unroll
        for (int ee = 0; ee < 4; ++ee) {
            int e = tid + ee * 256;       // 0..1023
            int r = e >> 3, c = (e & 7) * 8;
            *(short8*)&As[r][c] = *(const short8*)&A[(size_t)(row0 + r) * K + kt + c];
            *(short8*)&Bs[r][c] = *(const short8*)&Bt[(size_t)(col0 + r) * K + kt + c];
        }
        __syncthreads();
#pragma unroll
        for (int kk = 0; kk < 64; kk += 32) {
            short8 af[4], bf4[4];
#pragma unroll
            for (int mi = 0; mi < 4; ++mi)
                af[mi] = *(const short8*)&As[wr + mi * 16 + lr][kk + quad * 8];
#pragma unroll
            for (int ni = 0; ni < 4; ++ni)
                bf4[ni] = *(const short8*)&Bs[wc + ni * 16 + lr][kk + quad * 8];
#pragma unroll
            for (int mi = 0; mi < 4; ++mi)
#pragma unroll
                for (int ni = 0; ni < 4; ++ni)
                    acc[mi][ni] = __builtin_amdgcn_mfma_f32_16x16x32_bf16(
                        af[mi], bf4[ni], acc[mi][ni], 0, 0, 0);
        }
        __syncthreads();
    }
    int Ttm1 = (lt >= 0) ? ((1 << lt) - 1) : 0;
#pragma unroll
    for (int ni = 0; ni < 4; ++ni) {
        int gc = col0 + wc + ni * 16 + lr;
        float bi = bias[gc];
#pragma unroll
        for (int mi = 0; mi < 4; ++mi) {
            int gr0 = row0 + wr + mi * 16 + quad * 4;
            f32x4 vv = acc[mi][ni];
#pragma unroll
            for (int rr = 0; rr < 4; ++rr) {
                int r = gr0 + rr;
                float val = vv[rr] + bi;
                if (lt >= 0) {
                    int which = gc >> 9;          // 0=q,1=k,2=v (vt==2 fused)
                    int h2 = (gc >> 7) & 3, dh = gc & 127;
                    int mq = r >> lt, qi = r & Ttm1;
                    size_t base = (size_t)which * QCHUNK;
                    size_t oi;
                    if (which == 2) oi = base + ((((size_t)(mq * H_ + h2)) * DH_ + dh) << lt) + qi;
                    else            oi = base + ((((size_t)(mq * H_ + h2)) << lt) + qi) * DH_ + dh;
                    storeF(&C[oi], val);
                } else {
                    size_t oi = (size_t)r * N + gc;
                    if (addC) val += toF(C[oi]);
                    if (relu) val = fmaxf(val, 0.f);
                    storeF(&C[oi], val);
                }
            }
        }
    }
}

// ---- MFMA flash attention: block per (m, h, 64-query tile), 256 threads = 4 waves.
// q,k head-major [mh][Tt][128] bf16; v TRANSPOSED [mh][128][Tt] bf16.
// ctx row-major [M*Tt][512] bf16. Each wave owns 16 queries.
__global__ __launch_bounds__(256) void fused_attn(
    const bf16* __restrict__ q, const bf16* __restrict__ k, const bf16* __restrict__ vt,
    bf16* __restrict__ ctx, const int* __restrict__ lens, int Tt, int nqt) {
    __shared__ short Ks[64][136];       // 64 keys x 128 dh (+8 pad: 2-way banks)
    __shared__ short Vs[128][72];       // 128 dh x 64 keys (+8 pad)
    __shared__ short Ps[4][16][72];     // per-wave P tile: 16 q x 64 keys (+8 pad)
    int bx = blockIdx.x;
    int qt = bx % nqt, mh = bx / nqt;
    int m = mh >> 2, h = mh & 3;
    int tid  = threadIdx.x;
    int wave = tid >> 6, lane = tid & 63, lr = lane & 15, quad = lane >> 4;
    int q0 = qt * 64;
    int kvalid = Tt;
    if (lens) { int l0 = lens[m]; kvalid = l0 < 1 ? 1 : l0; }

    // Q A-fragments (A[m=lr][kk=quad*8+j]), loaded once from global
    short8 aq[4];
    const bf16* qrow = q + ((size_t)mh * Tt + q0 + wave * 16 + lr) * DH_;
#pragma unroll
    for (int ks2 = 0; ks2 < 4; ++ks2)
        aq[ks2] = *(const short8*)&qrow[ks2 * 32 + quad * 8];

    float mrow[4], lrow[4];
#pragma unroll
    for (int r = 0; r < 4; ++r) { mrow[r] = -INFINITY; lrow[r] = 0.f; }
    f32x4 acco[8];
    f32x4 zz = {0.f, 0.f, 0.f, 0.f};
#pragma unroll
    for (int n = 0; n < 8; ++n) acco[n] = zz;

    int nkt = Tt >> 6;
    for (int kt = 0; kt < nkt; ++kt) {
        int kb = kt * 64;
        __syncthreads();   // protect Ks/Vs reuse from previous iteration
        // stage K tile: 64 x 128 shorts = 1024 16B chunks, 4/thread
#pragma unroll
        for (int ee = 0; ee < 4; ++ee) {
            int e = tid + ee * 256;
            int r = e >> 4, c = (e & 15) * 8;
            *(short8*)&Ks[r][c] = *(const short8*)&k[((size_t)mh * Tt + kb + r) * DH_ + c];
        }
        // stage V^T tile: 128 rows x 64 shorts = 1024 16B chunks, 4/thread
#pragma unroll
        for (int ee = 0; ee < 4; ++ee) {
            int e = tid + ee * 256;
            int r = e >> 3, c = (e & 7) * 8;
            *(short8*)&Vs[r][c] = *(const short8*)&vt[((size_t)mh * DH_ + r) * Tt + kb + c];
        }
        __syncthreads();
        // ---- S = Q K^T : 4 key-tiles x 4 K-steps of MFMA 16x16x32 ----
        f32x4 s[4];
#pragma unroll
        for (int ni = 0; ni < 4; ++ni) s[ni] = zz;
#pragma unroll
        for (int ni = 0; ni < 4; ++ni)
#pragma unroll
            for (int ks2 = 0; ks2 < 4; ++ks2) {
                short8 kf = *(const short8*)&Ks[ni * 16 + lr][ks2 * 32 + quad * 8];
                s[ni] = __builtin_amdgcn_mfma_f32_16x16x32_bf16(aq[ks2], kf, s[ni], 0, 0, 0);
            }
        // ---- scale + mask; per-lane col = kb + ni*16 + lr; rows = quad*4+reg ----
        float mx[4] = {-INFINITY, -INFINITY, -INFINITY, -INFINITY};
#pragma unroll
        for (int ni = 0; ni < 4; ++ni) {
            bool ok = (kb + ni * 16 + lr) < kvalid;
#pragma unroll
            for (int reg = 0; reg < 4; ++reg) {
                float v = s[ni][reg] * 0.08838834764831845f;
                v = ok ? v : -INFINITY;
                s[ni][reg] = v;
                mx[reg] = fmaxf(mx[reg], v);
            }
        }
        // row-max across the 16 lanes of the quad
#pragma unroll
        for (int d2 = 1; d2 < 16; d2 <<= 1)
#pragma unroll
            for (int reg = 0; reg < 4; ++reg)
                mx[reg] = fmaxf(mx[reg], __shfl_xor(mx[reg], d2));
        float alpha[4];
#pragma unroll
        for (int reg = 0; reg < 4; ++reg) {
            float mn = fmaxf(mrow[reg], mx[reg]);
            alpha[reg] = __expf(mrow[reg] - mn);
            mrow[reg] = mn;
        }
        // ---- P = exp(s - m); row sums; write P to per-wave LDS (A-layout source) ----
        float rs[4] = {0.f, 0.f, 0.f, 0.f};
#pragma unroll
        for (int ni = 0; ni < 4; ++ni)
#pragma unroll
            for (int reg = 0; reg < 4; ++reg) {
                float p = __expf(s[ni][reg] - mrow[reg]);   // exp(-inf - finite) = 0
                s[ni][reg] = p;
                rs[reg] += p;
            }
#pragma unroll
        for (int d2 = 1; d2 < 16; d2 <<= 1)
#pragma unroll
            for (int reg = 0; reg < 4; ++reg)
                rs[reg] += __shfl_xor(rs[reg], d2);
#pragma unroll
        for (int reg = 0; reg < 4; ++reg)
            lrow[reg] = lrow[reg] * alpha[reg] + rs[reg];
#pragma unroll
        for (int ni = 0; ni < 4; ++ni)
#pragma unroll
            for (int reg = 0; reg < 4; ++reg)
                Ps[wave][quad * 4 + reg][ni * 16 + lr] = (short)f2b(s[ni][reg]);
        // ---- rescale O accumulator, then O += P V ----
#pragma unroll
        for (int n = 0; n < 8; ++n)
#pragma unroll
            for (int reg = 0; reg < 4; ++reg) acco[n][reg] *= alpha[reg];
#pragma unroll
        for (int ks2 = 0; ks2 < 2; ++ks2) {
            short8 pf = *(const short8*)&Ps[wave][lr][ks2 * 32 + quad * 8];
#pragma unroll
            for (int n = 0; n < 8; ++n) {
                short8 vf = *(const short8*)&Vs[n * 16 + lr][ks2 * 32 + quad * 8];
                acco[n] = __builtin_amdgcn_mfma_f32_16x16x32_bf16(pf, vf, acco[n], 0, 0, 0);
            }
        }
    }
    // ---- epilogue: divide by l, store ctx row-major ----
    float linv[4];
#pragma unroll
    for (int reg = 0; reg < 4; ++reg) linv[reg] = 1.f / lrow[reg];
#pragma unroll
    for (int n = 0; n < 8; ++n)
#pragma unroll
        for (int reg = 0; reg < 4; ++reg) {
            int qq = q0 + wave * 16 + quad * 4 + reg;
            ctx[((size_t)m * Tt + qq) * D_ + h * DH_ + n * 16 + lr] =
                __float2bfloat16(acco[n][reg] * linv[reg]);
        }
}

// ---- LayerNorm in place on bf16 (fp32 stats) ----
__global__ void ln_kernel(bf16* __restrict__ x,
                          const float* __restrict__ g,
                          const float* __restrict__ b) {
    int row = blockIdx.x;
    int t   = threadIdx.x;
    __shared__ float red[256];
    float v0 = toF(x[(size_t)row * D_ + t]);
    float v1 = toF(x[(size_t)row * D_ + t + 256]);
    red[t] = v0 + v1;
    __syncthreads();
    for (int off = 128; off > 0; off >>= 1) {
        if (t < off) red[t] += red[t + off];
        __syncthreads();
    }
    float mu = red[0] / 512.f;
    __syncthreads();
    float d0 = v0 - mu, d1 = v1 - mu;
    red[t] = d0 * d0 + d1 * d1;
    __syncthreads();
    for (int off = 128; off > 0; off >>= 1) {
        if (t < off) red[t] += red[t + off];
        __syncthreads();
    }
    float inv = rsqrtf(red[0] / 512.f + 1e-5f);
    x[(size_t)row * D_ + t]       = __float2bfloat16(d0 * inv * g[t] + b[t]);
    x[(size_t)row * D_ + t + 256] = __float2bfloat16(d1 * inv * g[t + 256] + b[t + 256]);
}

__global__ void copy_last_main(const bf16* __restrict__ x, float* __restrict__ bh) {
    int idx = blockIdx.x * blockDim.x + threadIdx.x;  // 64*512
    int b = idx >> 9, d = idx & 511;
    bh[idx] = toF(x[(size_t)(b * S_ + S_ - 1) * D_ + d]);
}

__global__ void add_last_kernel(const bf16* __restrict__ x,
                                const int* __restrict__ lens,
                                float* __restrict__ sep) {
    int idx = blockIdx.x * blockDim.x + threadIdx.x;  // 384*512
    int bn = idx >> 9, d = idx & 511;
    int len = lens[bn];
    float add = (len > 0) ? toF(x[(size_t)(bn * T_ + len - 1) * D_ + d]) : 0.f;
    sep[idx] += add;
}

__global__ void final_kernel(const float* __restrict__ sep,
                             const float* __restrict__ bh,
                             const int* __restrict__ nflag,
                             float* __restrict__ out) {
    int bn = blockIdx.x;
    int b  = bn / NH_;
    int t  = threadIdx.x;  // 256
    __shared__ float red[256];
    float v0 = sep[(size_t)bn * D_ + t];
    float v1 = sep[(size_t)bn * D_ + t + 256];
    int nf = nflag[0];
    float scale = 1.f;
    if (nf) {
        v0 = fmaxf(v0, 0.f);
        v1 = fmaxf(v1, 0.f);
        red[t] = v0 * v0 + v1 * v1;
        __syncthreads();
        for (int off = 128; off > 0; off >>= 1) {
            if (t < off) red[t] += red[t + off];
            __syncthreads();
        }
        scale = 1.f / fmaxf(sqrtf(red[0]), 1e-12f);
        __syncthreads();
    }
    red[t] = v0 * scale * bh[(size_t)b * D_ + t] + v1 * scale * bh[(size_t)b * D_ + t + 256];
    __syncthreads();
    for (int off = 128; off > 0; off >>= 1) {
        if (t < off) red[t] += red[t + off];
        __syncthreads();
    }
    if (t == 0) out[bn] = red[0];
}

extern "C" void kernel_launch(void* const* d_in, const int* in_sizes, int n_in,
                              void* d_out, int out_size, void* d_ws, size_t ws_size,
                              hipStream_t stream) {
    const int*   segment   = (const int*)d_in[0];
    const int*   prev_hist = (const int*)d_in[1];
    const int*   lens      = (const int*)d_in[2];
    const float* sep_img   = (const float*)d_in[3];
    const int*   normalize = (const int*)d_in[4];
    const float* emb       = (const float*)d_in[5];
    const float* Wq = (const float*)d_in[6];
    const float* bq = (const float*)d_in[7];
    const float* Wk = (const float*)d_in[8];
    const float* bk = (const float*)d_in[9];
    const float* Wv = (const float*)d_in[10];
    const float* bv = (const float*)d_in[11];
    const float* Wo = (const float*)d_in[12];
    const float* bo = (const float*)d_in[13];
    const float* ln1g = (const float*)d_in[14];
    const float* ln1b = (const float*)d_in[15];
    const float* W1 = (const float*)d_in[16];
    const float* b1 = (const float*)d_in[17];
    const float* W2 = (const float*)d_in[18];
    const float* b2 = (const float*)d_in[19];
    const float* ln2g = (const float*)d_in[20];
    const float* ln2b = (const float*)d_in[21];
    const float* Wsep = (const float*)d_in[22];
    const float* bsep = (const float*)d_in[23];
    float* out = (float*)d_out;

    // ---- workspace layout (~142 MiB) ----
    char* w = (char*)d_ws;
    float* bh   = (float*)w; w += (size_t)B_ * D_ * 4;
    float* sepb = (float*)w; w += (size_t)B_ * NH_ * D_ * 4;
    float* bqkv = (float*)w; w += (size_t)L_ * 1536 * 4;
    bf16* x16 = (bf16*)w; w += QCHUNK * 2;       // bf16 residual stream
    bf16* ctxb = (bf16*)w; w += QCHUNK * 2;      // attention context
    bf16* qh  = (bf16*)w; w += QCHUNK * 2;       // q head-major; also ffmid
    bf16* kh  = (bf16*)w; w += QCHUNK * 2;       // k head-major (qh + QCHUNK)
    bf16* vh  = (bf16*)w; w += QCHUNK * 2;       // V^T head-major (qh + 2*QCHUNK)
    bf16* sep16 = (bf16*)w; w += (size_t)B_ * NH_ * IMG_ * 2;
    bf16* Wqkvt = (bf16*)w; w += (size_t)L_ * 1536 * D_ * 2;  // [l][n=1536][k=512]
    bf16* Wot = (bf16*)w; w += (size_t)L_ * D_ * D_ * 2;
    bf16* W1t = (bf16*)w; w += (size_t)L_ * D_ * FF_ * 2;
    bf16* W2t = (bf16*)w; w += (size_t)L_ * FF_ * D_ * 2;
    bf16* Wsept = (bf16*)w; w += (size_t)IMG_ * D_ * 2;
    bf16* ffmid = qh;    // alias: q not needed after attention

    // ---- weight conversion (every call; inputs re-poisoned by harness) ----
    {
        dim3 tg(16, 16, L_);
        size_t qs = (size_t)1536 * D_;           // layer stride of Wqkvt
        transpose_cast<<<tg, 256, 0, stream>>>(Wq, Wqkvt,                 D_, D_, qs);
        transpose_cast<<<tg, 256, 0, stream>>>(Wk, Wqkvt + 512 * D_,      D_, D_, qs);
        transpose_cast<<<tg, 256, 0, stream>>>(Wv, Wqkvt + 1024 * D_,     D_, D_, qs);
        transpose_cast<<<tg, 256, 0, stream>>>(Wo, Wot, D_, D_, (size_t)D_ * D_);
        transpose_cast<<<tg, 256, 0, stream>>>(W1, W1t, D_, FF_, (size_t)D_ * FF_);
        transpose_cast<<<tg, 256, 0, stream>>>(W2, W2t, FF_, D_, (size_t)FF_ * D_);
        transpose_cast<<<dim3(16, 64, 1), 256, 0, stream>>>(Wsep, Wsept, IMG_, D_,
                                                            (size_t)IMG_ * D_);
        gather_qkv_bias<<<(L_ * 1536 + 255) / 256, 256, 0, stream>>>(bq, bk, bv, bqkv);
        int n = B_ * NH_ * IMG_;
        cast_bf16<<<(n + 255) / 256, 256, 0, stream>>>(sep_img, sep16, n);
    }

    auto run_encoder = [&](int M, int Tt, int lt, const int* lens_p) {
        int NT = M * Tt;
        dim3 gg(D_ / 128, NT / 128);
        dim3 gq(1536 / 128, NT / 128);
        int nqt = Tt / 64;
        for (int l = 0; l < L_; ++l) {
            // fused q,k,v GEMM: N=1536, epilogue scatters to qh/kh/vh chunks
            gemm_mfma<bf16><<<gq, 256, 0, stream>>>(
                x16, Wqkvt + (size_t)l * 1536 * D_, bqkv + l * 1536, qh,
                NT, 1536, D_, lt, 0, 0, 2);
            fused_attn<<<M * H_ * nqt, 256, 0, stream>>>(
                qh, kh, vh, ctxb, lens_p, Tt, nqt);
            gemm_mfma<bf16><<<gg, 256, 0, stream>>>(
                ctxb, Wot + (size_t)l * D_ * D_, bo + l * D_, x16,
                NT, D_, D_, -1, 0, 1, 0);  // += resid
            ln_kernel<<<NT, 256, 0, stream>>>(x16, ln1g + l * D_, ln1b + l * D_);
            gemm_mfma<bf16><<<gg, 256, 0, stream>>>(
                x16, W1t + (size_t)l * D_ * FF_, b1 + l * FF_, ffmid,
                NT, FF_, D_, -1, 1, 0, 0);
            gemm_mfma<bf16><<<gg, 256, 0, stream>>>(
                ffmid, W2t + (size_t)l * FF_ * D_, b2 + l * D_, x16,
                NT, D_, FF_, -1, 0, 1, 0); // += resid
            ln_kernel<<<NT, 256, 0, stream>>>(x16, ln2g + l * D_, ln2b + l * D_);
        }
    };

    // ---- main encoder: M=64, Tt=256 (lt=8), no mask ----
    {
        int total = B_ * S_ * D_;
        embed_kernel<<<total / 256, 256, 0, stream>>>(segment, emb, x16, S_, total);
    }
    run_encoder(B_, S_, 8, nullptr);
    copy_last_main<<<(B_ * D_) / 256, 256, 0, stream>>>(x16, bh);

    // ---- sep = separate_images @ Wsep + bsep : (384 x 2048) @ (2048 x 512) ----
    gemm_mfma<float><<<dim3(D_ / 128, (B_ * NH_) / 128), 256, 0, stream>>>(
        sep16, Wsept, bsep, sepb, B_ * NH_, D_, IMG_, -1, 0, 0, 0);

    // ---- history encoder: M=384, Tt=64 (lt=6), key mask from lens ----
    {
        int total = B_ * NH_ * T_ * D_;
        embed_kernel<<<total / 256, 256, 0, stream>>>(prev_hist, emb, x16, T_, total);
    }
    run_encoder(B_ * NH_, T_, 6, lens);

    add_last_kernel<<<(B_ * NH_ * D_) / 256, 256, 0, stream>>>(x16, lens, sepb);
    final_kernel<<<B_ * NH_, 256, 0, stream>>>(sepb, bh, normalize, out);
}

// Round 9
// 2239.705 us; speedup vs baseline: 1.1229x; 1.1229x over previous
//
#include <hip/hip_runtime.h>
#include <hip/hip_bf16.h>
#include <math.h>

typedef __hip_bfloat16 bf16;
typedef __attribute__((ext_vector_type(8))) short short8;
typedef __attribute__((ext_vector_type(4))) float f32x4;

#define D_    512
#define H_    4
#define DH_   128
#define L_    4
#define FF_   512
#define B_    64
#define NH_   6
#define S_    256
#define T_    64
#define IMG_  2048
#define NTMAX 24576
#define QCHUNK ((size_t)NTMAX * D_)   // element stride between q,k,v buffers

// async global->LDS, 16B per lane, LDS dest = wave-uniform base + lane*16
#define GLOAD_LDS(gp, lp) __builtin_amdgcn_global_load_lds( \
    (const __attribute__((address_space(1))) void*)(gp),    \
    (__attribute__((address_space(3))) void*)(lp), 16, 0, 0)

__device__ __forceinline__ float toF(bf16 v)  { return __bfloat162float(v); }
__device__ __forceinline__ float toF(float v) { return v; }
__device__ __forceinline__ void storeF(bf16* p, float v)  { *p = __float2bfloat16(v); }
__device__ __forceinline__ void storeF(float* p, float v) { *p = v; }

// round-to-nearest-even f32 -> bf16 bits
__device__ __forceinline__ unsigned short f2b(float f) {
    unsigned u = __float_as_uint(f);
    unsigned r = (u + 0x7fffu + ((u >> 16) & 1u)) >> 16;
    return (unsigned short)r;
}

// ---- weight transpose + cast: src[R][C] fp32 -> dst[C][R] bf16, z = layer.
// src layer stride R*Cc, dst layer stride dstride (elements).
__global__ void transpose_cast(const float* __restrict__ src, bf16* __restrict__ dst,
                               int R, int Cc, size_t dstride) {
    __shared__ float t[32][33];
    src += (size_t)blockIdx.z * R * Cc;
    dst += (size_t)blockIdx.z * dstride;
    int c0 = blockIdx.x * 32, r0 = blockIdx.y * 32;
    int tx = threadIdx.x & 31, ty = threadIdx.x >> 5;  // 256 thr: ty 0..7
    for (int i = ty; i < 32; i += 8) t[i][tx] = src[(size_t)(r0 + i) * Cc + c0 + tx];
    __syncthreads();
    for (int i = ty; i < 32; i += 8)
        dst[(size_t)(c0 + i) * R + r0 + tx] = __float2bfloat16(t[tx][i]);
}

// ---- flat f32 -> bf16 cast ----
__global__ void cast_bf16(const float* __restrict__ src, bf16* __restrict__ dst, int n) {
    int i = blockIdx.x * blockDim.x + threadIdx.x;
    if (i < n) dst[i] = __float2bfloat16(src[i]);
}

// ---- gather qkv bias: o[l][0:512]=bq[l], [512:1024]=bk[l], [1024:1536]=bv[l] ----
__global__ void gather_qkv_bias(const float* __restrict__ bq, const float* __restrict__ bk,
                                const float* __restrict__ bv, float* __restrict__ o) {
    int idx = blockIdx.x * blockDim.x + threadIdx.x;  // L_*1536 = 6144
    if (idx >= L_ * 1536) return;
    int l = idx / 1536, j = idx - l * 1536;
    int which = j >> 9, rem = j & 511;
    const float* s = (which == 0) ? bq : (which == 1) ? bk : bv;
    o[idx] = s[l * 512 + rem];
}

// ---- embedding + positional encoding: bf16 out ----
__global__ void embed_kernel(const int* __restrict__ tokens,
                             const float* __restrict__ emb,
                             bf16* __restrict__ x16,
                             int Tt, int total) {
    int idx = blockIdx.x * blockDim.x + threadIdx.x;
    if (idx >= total) return;
    int d   = idx & (D_ - 1);
    int row = idx >> 9;
    int t   = row % Tt;
    int tok = tokens[row];
    int i   = d >> 1;
    float ex  = -(float)(2 * i) * (9.210340371976184f / 512.0f);
    float dv  = expf(ex);
    float ang = (float)t * dv;
    float pe  = (d & 1) ? cosf(ang) : sinf(ang);
    x16[idx] = __float2bfloat16(emb[(size_t)tok * D_ + d] + pe);
}

// ---- MFMA bf16 GEMM: C[M,N] = A[M,K] @ B[K,N] + bias, B given transposed Bt[N][K]
// 128x128 tile, BK=64, 4 waves each computing 64x64 via 4x4 MFMAs 16x16x32.
// Staging: global_load_lds width=16, unpadded [128][64] LDS tiles with XOR chunk
// swizzle — LDS row r position cpos holds global chunk (cpos ^ (r&7)); fragment
// reads use chunk ((4ks+quad) ^ (lr&7)) -> 2-way max bank aliasing (free).
// lt < 0 : row-major out, optional addC (in-place += on C) and relu.
// lt >= 0 (fused qkv, N=1536): which=gc>>9 selects chunk C + which*QCHUNK;
//   which 0,1 (q,k): head-major out[((mq*H+h)*Tt + qi)*128 + dh], Tt=1<<lt
//   which 2   (v) : transposed  out[((mq*H+h)*128 + dh)*Tt + qi]
template <typename CT>
__global__ __launch_bounds__(256) void gemm_mfma(
    const bf16* __restrict__ A, const bf16* __restrict__ Bt,
    const float* __restrict__ bias, CT* __restrict__ C,
    int M, int N, int K, int lt, int relu, int addC, int vt) {
    __shared__ short As[128 * 64];
    __shared__ short Bs[128 * 64];
    int tid  = threadIdx.x;
    int wave = tid >> 6, lane = tid & 63, lr = lane & 15, quad = lane >> 4;
    int wr = (wave >> 1) * 64, wc = (wave & 1) * 64;
    int bx = blockIdx.x, by = blockIdx.y;
    if ((gridDim.y & 7) == 0) {
        int id = by * gridDim.x + bx;
        int xcd = id & 7, slot = id >> 3;
        by = xcd + 8 * (slot / gridDim.x);
        bx = slot % gridDim.x;
    }
    int row0 = by * 128, col0 = bx * 128;
    // staging geometry: 16 segments of 8 rows; wave w stages segments w,w+4,w+8,w+12.
    // lane i covers row (i>>3), chunk-position (i&7); global chunk = (i&7)^(i>>3).
    int srow   = lane >> 3;                    // 0..7 within segment
    int gchunk = (lane & 7) ^ srow;            // swizzled source chunk
    f32x4 acc[4][4];
    f32x4 zz = {0.f, 0.f, 0.f, 0.f};
#pragma unroll
    for (int mi = 0; mi < 4; ++mi)
#pragma unroll
        for (int ni = 0; ni < 4; ++ni) acc[mi][ni] = zz;

    int lr7 = lr & 7;
    for (int kt = 0; kt < K; kt += 64) {
#pragma unroll
        for (int sseg = 0; sseg < 4; ++sseg) {
            int s = wave + sseg * 4;           // segment 0..15
            int rloc = s * 8 + srow;
            const bf16* gA = &A[(size_t)(row0 + rloc) * K + kt + gchunk * 8];
            const bf16* gB = &Bt[(size_t)(col0 + rloc) * K + kt + gchunk * 8];
            GLOAD_LDS(gA, &As[s * 512]);
            GLOAD_LDS(gB, &Bs[s * 512]);
        }
        __syncthreads();   // drains vmcnt (async LDS writes) + barrier
#pragma unroll
        for (int ks = 0; ks < 2; ++ks) {
            int cp = (((ks * 4) + quad) ^ lr7) * 8;
            short8 af[4], bf4[4];
#pragma unroll
            for (int mi = 0; mi < 4; ++mi)
                af[mi] = *(const short8*)&As[(wr + mi * 16 + lr) * 64 + cp];
#pragma unroll
            for (int ni = 0; ni < 4; ++ni)
                bf4[ni] = *(const short8*)&Bs[(wc + ni * 16 + lr) * 64 + cp];
#pragma unroll
            for (int mi = 0; mi < 4; ++mi)
#pragma unroll
                for (int ni = 0; ni < 4; ++ni)
                    acc[mi][ni] = __builtin_amdgcn_mfma_f32_16x16x32_bf16(
                        af[mi], bf4[ni], acc[mi][ni], 0, 0, 0);
        }
        __syncthreads();   // protect LDS reuse before next iteration's async writes
    }
    int Ttm1 = (lt >= 0) ? ((1 << lt) - 1) : 0;
#pragma unroll
    for (int ni = 0; ni < 4; ++ni) {
        int gc = col0 + wc + ni * 16 + lr;
        float bi = bias[gc];
#pragma unroll
        for (int mi = 0; mi < 4; ++mi) {
            int gr0 = row0 + wr + mi * 16 + quad * 4;
            f32x4 vv = acc[mi][ni];
#pragma unroll
            for (int rr = 0; rr < 4; ++rr) {
                int r = gr0 + rr;
                float val = vv[rr] + bi;
                if (lt >= 0) {
                    int which = gc >> 9;          // 0=q,1=k,2=v (fused qkv)
                    int h2 = (gc >> 7) & 3, dh = gc & 127;
                    int mq = r >> lt, qi = r & Ttm1;
                    size_t base = (size_t)which * QCHUNK;
                    size_t oi;
                    if (which == 2) oi = base + ((((size_t)(mq * H_ + h2)) * DH_ + dh) << lt) + qi;
                    else            oi = base + ((((size_t)(mq * H_ + h2)) << lt) + qi) * DH_ + dh;
                    storeF(&C[oi], val);
                } else {
                    size_t oi = (size_t)r * N + gc;
                    if (addC) val += toF(C[oi]);
                    if (relu) val = fmaxf(val, 0.f);
                    storeF(&C[oi], val);
                }
            }
        }
    }
}

// ---- MFMA flash attention: block per (m, h, 64-query tile), 256 threads = 4 waves.
// q,k head-major [mh][Tt][128] bf16; v TRANSPOSED [mh][128][Tt] bf16.
// ctx row-major [M*Tt][512] bf16. Each wave owns 16 queries.
__global__ __launch_bounds__(256) void fused_attn(
    const bf16* __restrict__ q, const bf16* __restrict__ k, const bf16* __restrict__ vt,
    bf16* __restrict__ ctx, const int* __restrict__ lens, int Tt, int nqt) {
    __shared__ short Ks[64][136];       // 64 keys x 128 dh (+8 pad: 2-way banks)
    __shared__ short Vs[128][72];       // 128 dh x 64 keys (+8 pad)
    __shared__ short Ps[4][16][72];     // per-wave P tile: 16 q x 64 keys (+8 pad)
    int bx = blockIdx.x;
    int qt = bx % nqt, mh = bx / nqt;
    int m = mh >> 2, h = mh & 3;
    int tid  = threadIdx.x;
    int wave = tid >> 6, lane = tid & 63, lr = lane & 15, quad = lane >> 4;
    int q0 = qt * 64;
    int kvalid = Tt;
    if (lens) { int l0 = lens[m]; kvalid = l0 < 1 ? 1 : l0; }

    // Q A-fragments (A[m=lr][kk=quad*8+j]), loaded once from global
    short8 aq[4];
    const bf16* qrow = q + ((size_t)mh * Tt + q0 + wave * 16 + lr) * DH_;
#pragma unroll
    for (int ks2 = 0; ks2 < 4; ++ks2)
        aq[ks2] = *(const short8*)&qrow[ks2 * 32 + quad * 8];

    float mrow[4], lrow[4];
#pragma unroll
    for (int r = 0; r < 4; ++r) { mrow[r] = -INFINITY; lrow[r] = 0.f; }
    f32x4 acco[8];
    f32x4 zz = {0.f, 0.f, 0.f, 0.f};
#pragma unroll
    for (int n = 0; n < 8; ++n) acco[n] = zz;

    int nkt = Tt >> 6;
    for (int kt = 0; kt < nkt; ++kt) {
        int kb = kt * 64;
        __syncthreads();   // protect Ks/Vs reuse from previous iteration
        // stage K tile: 64 x 128 shorts = 1024 16B chunks, 4/thread
#pragma unroll
        for (int ee = 0; ee < 4; ++ee) {
            int e = tid + ee * 256;
            int r = e >> 4, c = (e & 15) * 8;
            *(short8*)&Ks[r][c] = *(const short8*)&k[((size_t)mh * Tt + kb + r) * DH_ + c];
        }
        // stage V^T tile: 128 rows x 64 shorts = 1024 16B chunks, 4/thread
#pragma unroll
        for (int ee = 0; ee < 4; ++ee) {
            int e = tid + ee * 256;
            int r = e >> 3, c = (e & 7) * 8;
            *(short8*)&Vs[r][c] = *(const short8*)&vt[((size_t)mh * DH_ + r) * Tt + kb + c];
        }
        __syncthreads();
        // ---- S = Q K^T : 4 key-tiles x 4 K-steps of MFMA 16x16x32 ----
        f32x4 s[4];
#pragma unroll
        for (int ni = 0; ni < 4; ++ni) s[ni] = zz;
#pragma unroll
        for (int ni = 0; ni < 4; ++ni)
#pragma unroll
            for (int ks2 = 0; ks2 < 4; ++ks2) {
                short8 kf = *(const short8*)&Ks[ni * 16 + lr][ks2 * 32 + quad * 8];
                s[ni] = __builtin_amdgcn_mfma_f32_16x16x32_bf16(aq[ks2], kf, s[ni], 0, 0, 0);
            }
        // ---- scale + mask; per-lane col = kb + ni*16 + lr; rows = quad*4+reg ----
        float mx[4] = {-INFINITY, -INFINITY, -INFINITY, -INFINITY};
#pragma unroll
        for (int ni = 0; ni < 4; ++ni) {
            bool ok = (kb + ni * 16 + lr) < kvalid;
#pragma unroll
            for (int reg = 0; reg < 4; ++reg) {
                float v = s[ni][reg] * 0.08838834764831845f;
                v = ok ? v : -INFINITY;
                s[ni][reg] = v;
                mx[reg] = fmaxf(mx[reg], v);
            }
        }
        // row-max across the 16 lanes of the quad
#pragma unroll
        for (int d2 = 1; d2 < 16; d2 <<= 1)
#pragma unroll
            for (int reg = 0; reg < 4; ++reg)
                mx[reg] = fmaxf(mx[reg], __shfl_xor(mx[reg], d2));
        float alpha[4];
#pragma unroll
        for (int reg = 0; reg < 4; ++reg) {
            float mn = fmaxf(mrow[reg], mx[reg]);
            alpha[reg] = __expf(mrow[reg] - mn);
            mrow[reg] = mn;
        }
        // ---- P = exp(s - m); row sums; write P to per-wave LDS (A-layout source) ----
        float rs[4] = {0.f, 0.f, 0.f, 0.f};
#pragma unroll
        for (int ni = 0; ni < 4; ++ni)
#pragma unroll
            for (int reg = 0; reg < 4; ++reg) {
                float p = __expf(s[ni][reg] - mrow[reg]);   // exp(-inf - finite) = 0
                s[ni][reg] = p;
                rs[reg] += p;
            }
#pragma unroll
        for (int d2 = 1; d2 < 16; d2 <<= 1)
#pragma unroll
            for (int reg = 0; reg < 4; ++reg)
                rs[reg] += __shfl_xor(rs[reg], d2);
#pragma unroll
        for (int reg = 0; reg < 4; ++reg)
            lrow[reg] = lrow[reg] * alpha[reg] + rs[reg];
#pragma unroll
        for (int ni = 0; ni < 4; ++ni)
#pragma unroll
            for (int reg = 0; reg < 4; ++reg)
                Ps[wave][quad * 4 + reg][ni * 16 + lr] = (short)f2b(s[ni][reg]);
        // ---- rescale O accumulator, then O += P V ----
#pragma unroll
        for (int n = 0; n < 8; ++n)
#pragma unroll
            for (int reg = 0; reg < 4; ++reg) acco[n][reg] *= alpha[reg];
#pragma unroll
        for (int ks2 = 0; ks2 < 2; ++ks2) {
            short8 pf = *(const short8*)&Ps[wave][lr][ks2 * 32 + quad * 8];
#pragma unroll
            for (int n = 0; n < 8; ++n) {
                short8 vf = *(const short8*)&Vs[n * 16 + lr][ks2 * 32 + quad * 8];
                acco[n] = __builtin_amdgcn_mfma_f32_16x16x32_bf16(pf, vf, acco[n], 0, 0, 0);
            }
        }
    }
    // ---- epilogue: divide by l, store ctx row-major ----
    float linv[4];
#pragma unroll
    for (int reg = 0; reg < 4; ++reg) linv[reg] = 1.f / lrow[reg];
#pragma unroll
    for (int n = 0; n < 8; ++n)
#pragma unroll
        for (int reg = 0; reg < 4; ++reg) {
            int qq = q0 + wave * 16 + quad * 4 + reg;
            ctx[((size_t)m * Tt + qq) * D_ + h * DH_ + n * 16 + lr] =
                __float2bfloat16(acco[n][reg] * linv[reg]);
        }
}

// ---- LayerNorm in place on bf16 (fp32 stats) ----
__global__ void ln_kernel(bf16* __restrict__ x,
                          const float* __restrict__ g,
                          const float* __restrict__ b) {
    int row = blockIdx.x;
    int t   = threadIdx.x;
    __shared__ float red[256];
    float v0 = toF(x[(size_t)row * D_ + t]);
    float v1 = toF(x[(size_t)row * D_ + t + 256]);
    red[t] = v0 + v1;
    __syncthreads();
    for (int off = 128; off > 0; off >>= 1) {
        if (t < off) red[t] += red[t + off];
        __syncthreads();
    }
    float mu = red[0] / 512.f;
    __syncthreads();
    float d0 = v0 - mu, d1 = v1 - mu;
    red[t] = d0 * d0 + d1 * d1;
    __syncthreads();
    for (int off = 128; off > 0; off >>= 1) {
        if (t < off) red[t] += red[t + off];
        __syncthreads();
    }
    float inv = rsqrtf(red[0] / 512.f + 1e-5f);
    x[(size_t)row * D_ + t]       = __float2bfloat16(d0 * inv * g[t] + b[t]);
    x[(size_t)row * D_ + t + 256] = __float2bfloat16(d1 * inv * g[t + 256] + b[t + 256]);
}

__global__ void copy_last_main(const bf16* __restrict__ x, float* __restrict__ bh) {
    int idx = blockIdx.x * blockDim.x + threadIdx.x;  // 64*512
    int b = idx >> 9, d = idx & 511;
    bh[idx] = toF(x[(size_t)(b * S_ + S_ - 1) * D_ + d]);
}

__global__ void add_last_kernel(const bf16* __restrict__ x,
                                const int* __restrict__ lens,
                                float* __restrict__ sep) {
    int idx = blockIdx.x * blockDim.x + threadIdx.x;  // 384*512
    int bn = idx >> 9, d = idx & 511;
    int len = lens[bn];
    float add = (len > 0) ? toF(x[(size_t)(bn * T_ + len - 1) * D_ + d]) : 0.f;
    sep[idx] += add;
}

__global__ void final_kernel(const float* __restrict__ sep,
                             const float* __restrict__ bh,
                             const int* __restrict__ nflag,
                             float* __restrict__ out) {
    int bn = blockIdx.x;
    int b  = bn / NH_;
    int t  = threadIdx.x;  // 256
    __shared__ float red[256];
    float v0 = sep[(size_t)bn * D_ + t];
    float v1 = sep[(size_t)bn * D_ + t + 256];
    int nf = nflag[0];
    float scale = 1.f;
    if (nf) {
        v0 = fmaxf(v0, 0.f);
        v1 = fmaxf(v1, 0.f);
        red[t] = v0 * v0 + v1 * v1;
        __syncthreads();
        for (int off = 128; off > 0; off >>= 1) {
            if (t < off) red[t] += red[t + off];
            __syncthreads();
        }
        scale = 1.f / fmaxf(sqrtf(red[0]), 1e-12f);
        __syncthreads();
    }
    red[t] = v0 * scale * bh[(size_t)b * D_ + t] + v1 * scale * bh[(size_t)b * D_ + t + 256];
    __syncthreads();
    for (int off = 128; off > 0; off >>= 1) {
        if (t < off) red[t] += red[t + off];
        __syncthreads();
    }
    if (t == 0) out[bn] = red[0];
}

extern "C" void kernel_launch(void* const* d_in, const int* in_sizes, int n_in,
                              void* d_out, int out_size, void* d_ws, size_t ws_size,
                              hipStream_t stream) {
    const int*   segment   = (const int*)d_in[0];
    const int*   prev_hist = (const int*)d_in[1];
    const int*   lens      = (const int*)d_in[2];
    const float* sep_img   = (const float*)d_in[3];
    const int*   normalize = (const int*)d_in[4];
    const float* emb       = (const float*)d_in[5];
    const float* Wq = (const float*)d_in[6];
    const float* bq = (const float*)d_in[7];
    const float* Wk = (const float*)d_in[8];
    const float* bk = (const float*)d_in[9];
    const float* Wv = (const float*)d_in[10];
    const float* bv = (const float*)d_in[11];
    const float* Wo = (const float*)d_in[12];
    const float* bo = (const float*)d_in[13];
    const float* ln1g = (const float*)d_in[14];
    const float* ln1b = (const float*)d_in[15];
    const float* W1 = (const float*)d_in[16];
    const float* b1 = (const float*)d_in[17];
    const float* W2 = (const float*)d_in[18];
    const float* b2 = (const float*)d_in[19];
    const float* ln2g = (const float*)d_in[20];
    const float* ln2b = (const float*)d_in[21];
    const float* Wsep = (const float*)d_in[22];
    const float* bsep = (const float*)d_in[23];
    float* out = (float*)d_out;

    // ---- workspace layout (~142 MiB) ----
    char* w = (char*)d_ws;
    float* bh   = (float*)w; w += (size_t)B_ * D_ * 4;
    float* sepb = (float*)w; w += (size_t)B_ * NH_ * D_ * 4;
    float* bqkv = (float*)w; w += (size_t)L_ * 1536 * 4;
    bf16* x16 = (bf16*)w; w += QCHUNK * 2;       // bf16 residual stream
    bf16* ctxb = (bf16*)w; w += QCHUNK * 2;      // attention context
    bf16* qh  = (bf16*)w; w += QCHUNK * 2;       // q head-major; also ffmid
    bf16* kh  = (bf16*)w; w += QCHUNK * 2;       // k head-major (qh + QCHUNK)
    bf16* vh  = (bf16*)w; w += QCHUNK * 2;       // V^T head-major (qh + 2*QCHUNK)
    bf16* sep16 = (bf16*)w; w += (size_t)B_ * NH_ * IMG_ * 2;
    bf16* Wqkvt = (bf16*)w; w += (size_t)L_ * 1536 * D_ * 2;  // [l][n=1536][k=512]
    bf16* Wot = (bf16*)w; w += (size_t)L_ * D_ * D_ * 2;
    bf16* W1t = (bf16*)w; w += (size_t)L_ * D_ * FF_ * 2;
    bf16* W2t = (bf16*)w; w += (size_t)L_ * FF_ * D_ * 2;
    bf16* Wsept = (bf16*)w; w += (size_t)IMG_ * D_ * 2;
    bf16* ffmid = qh;    // alias: q not needed after attention

    // ---- weight conversion (every call; inputs re-poisoned by harness) ----
    {
        dim3 tg(16, 16, L_);
        size_t qs = (size_t)1536 * D_;           // layer stride of Wqkvt
        transpose_cast<<<tg, 256, 0, stream>>>(Wq, Wqkvt,                 D_, D_, qs);
        transpose_cast<<<tg, 256, 0, stream>>>(Wk, Wqkvt + 512 * D_,      D_, D_, qs);
        transpose_cast<<<tg, 256, 0, stream>>>(Wv, Wqkvt + 1024 * D_,     D_, D_, qs);
        transpose_cast<<<tg, 256, 0, stream>>>(Wo, Wot, D_, D_, (size_t)D_ * D_);
        transpose_cast<<<tg, 256, 0, stream>>>(W1, W1t, D_, FF_, (size_t)D_ * FF_);
        transpose_cast<<<tg, 256, 0, stream>>>(W2, W2t, FF_, D_, (size_t)FF_ * D_);
        transpose_cast<<<dim3(16, 64, 1), 256, 0, stream>>>(Wsep, Wsept, IMG_, D_,
                                                            (size_t)IMG_ * D_);
        gather_qkv_bias<<<(L_ * 1536 + 255) / 256, 256, 0, stream>>>(bq, bk, bv, bqkv);
        int n = B_ * NH_ * IMG_;
        cast_bf16<<<(n + 255) / 256, 256, 0, stream>>>(sep_img, sep16, n);
    }

    auto run_encoder = [&](int M, int Tt, int lt, const int* lens_p) {
        int NT = M * Tt;
        dim3 gg(D_ / 128, NT / 128);
        dim3 gq(1536 / 128, NT / 128);
        int nqt = Tt / 64;
        for (int l = 0; l < L_; ++l) {
            // fused q,k,v GEMM: N=1536, epilogue scatters to qh/kh/vh chunks
            gemm_mfma<bf16><<<gq, 256, 0, stream>>>(
                x16, Wqkvt + (size_t)l * 1536 * D_, bqkv + l * 1536, qh,
                NT, 1536, D_, lt, 0, 0, 2);
            fused_attn<<<M * H_ * nqt, 256, 0, stream>>>(
                qh, kh, vh, ctxb, lens_p, Tt, nqt);
            gemm_mfma<bf16><<<gg, 256, 0, stream>>>(
                ctxb, Wot + (size_t)l * D_ * D_, bo + l * D_, x16,
                NT, D_, D_, -1, 0, 1, 0);  // += resid
            ln_kernel<<<NT, 256, 0, stream>>>(x16, ln1g + l * D_, ln1b + l * D_);
            gemm_mfma<bf16><<<gg, 256, 0, stream>>>(
                x16, W1t + (size_t)l * D_ * FF_, b1 + l * FF_, ffmid,
                NT, FF_, D_, -1, 1, 0, 0);
            gemm_mfma<bf16><<<gg, 256, 0, stream>>>(
                ffmid, W2t + (size_t)l * FF_ * D_, b2 + l * D_, x16,
                NT, D_, FF_, -1, 0, 1, 0); // += resid
            ln_kernel<<<NT, 256, 0, stream>>>(x16, ln2g + l * D_, ln2b + l * D_);
        }
    };

    // ---- main encoder: M=64, Tt=256 (lt=8), no mask ----
    {
        int total = B_ * S_ * D_;
        embed_kernel<<<total / 256, 256, 0, stream>>>(segment, emb, x16, S_, total);
    }
    run_encoder(B_, S_, 8, nullptr);
    copy_last_main<<<(B_ * D_) / 256, 256, 0, stream>>>(x16, bh);

    // ---- sep = separate_images @ Wsep + bsep : (384 x 2048) @ (2048 x 512) ----
    gemm_mfma<float><<<dim3(D_ / 128, (B_ * NH_) / 128), 256, 0, stream>>>(
        sep16, Wsept, bsep, sepb, B_ * NH_, D_, IMG_, -1, 0, 0, 0);

    // ---- history encoder: M=384, Tt=64 (lt=6), key mask from lens ----
    {
        int total = B_ * NH_ * T_ * D_;
        embed_kernel<<<total / 256, 256, 0, stream>>>(prev_hist, emb, x16, T_, total);
    }
    run_encoder(B_ * NH_, T_, 6, lens);

    add_last_kernel<<<(B_ * NH_ * D_) / 256, 256, 0, stream>>>(x16, lens, sepb);
    final_kernel<<<B_ * NH_, 256, 0, stream>>>(sepb, bh, normalize, out);
}

// Round 10
// 2163.388 us; speedup vs baseline: 1.1626x; 1.0353x over previous
//
#include <hip/hip_runtime.h>
#include <hip/hip_bf16.h>
#include <math.h>

typedef __hip_bfloat16 bf16;
typedef __attribute__((ext_vector_type(8))) short short8;
typedef __attribute__((ext_vector_type(4))) float f32x4;

#define D_    512
#define H_    4
#define DH_   128
#define L_    4
#define FF_   512
#define B_    64
#define NH_   6
#define S_    256
#define T_    64
#define IMG_  2048
#define NTMAIN (B_ * S_)              // 16384
#define NTHIST (B_ * NH_ * T_)        // 24576
#define NTALL  (NTMAIN + NTHIST)      // 40960
#define QCHUNK ((size_t)NTHIST * D_)  // element stride between q,k,v buffers

// async global->LDS, 16B per lane, LDS dest = wave-uniform base + lane*16
#define GLOAD_LDS(gp, lp) __builtin_amdgcn_global_load_lds( \
    (const __attribute__((address_space(1))) void*)(gp),    \
    (__attribute__((address_space(3))) void*)(lp), 16, 0, 0)

__device__ __forceinline__ float toF(bf16 v)  { return __bfloat162float(v); }
__device__ __forceinline__ float toF(float v) { return v; }
__device__ __forceinline__ void storeF(bf16* p, float v)  { *p = __float2bfloat16(v); }
__device__ __forceinline__ void storeF(float* p, float v) { *p = v; }

// round-to-nearest-even f32 -> bf16 bits
__device__ __forceinline__ unsigned short f2b(float f) {
    unsigned u = __float_as_uint(f);
    unsigned r = (u + 0x7fffu + ((u >> 16) & 1u)) >> 16;
    return (unsigned short)r;
}

// ---- weight transpose + cast: src[R][C] fp32 -> dst[C][R] bf16, z = layer ----
__global__ void transpose_cast(const float* __restrict__ src, bf16* __restrict__ dst,
                               int R, int Cc, size_t dstride) {
    __shared__ float t[32][33];
    src += (size_t)blockIdx.z * R * Cc;
    dst += (size_t)blockIdx.z * dstride;
    int c0 = blockIdx.x * 32, r0 = blockIdx.y * 32;
    int tx = threadIdx.x & 31, ty = threadIdx.x >> 5;  // 256 thr: ty 0..7
    for (int i = ty; i < 32; i += 8) t[i][tx] = src[(size_t)(r0 + i) * Cc + c0 + tx];
    __syncthreads();
    for (int i = ty; i < 32; i += 8)
        dst[(size_t)(c0 + i) * R + r0 + tx] = __float2bfloat16(t[tx][i]);
}

// ---- flat f32 -> bf16 cast ----
__global__ void cast_bf16(const float* __restrict__ src, bf16* __restrict__ dst, int n) {
    int i = blockIdx.x * blockDim.x + threadIdx.x;
    if (i < n) dst[i] = __float2bfloat16(src[i]);
}

// ---- gather qkv bias: o[l][0:512]=bq[l], [512:1024]=bk[l], [1024:1536]=bv[l] ----
__global__ void gather_qkv_bias(const float* __restrict__ bq, const float* __restrict__ bk,
                                const float* __restrict__ bv, float* __restrict__ o) {
    int idx = blockIdx.x * blockDim.x + threadIdx.x;  // L_*1536 = 6144
    if (idx >= L_ * 1536) return;
    int l = idx / 1536, j = idx - l * 1536;
    int which = j >> 9, rem = j & 511;
    const float* s = (which == 0) ? bq : (which == 1) ? bk : bv;
    o[idx] = s[l * 512 + rem];
}

// ---- embedding + positional encoding: bf16 out ----
__global__ void embed_kernel(const int* __restrict__ tokens,
                             const float* __restrict__ emb,
                             bf16* __restrict__ x16,
                             int Tt, int total) {
    int idx = blockIdx.x * blockDim.x + threadIdx.x;
    if (idx >= total) return;
    int d   = idx & (D_ - 1);
    int row = idx >> 9;
    int t   = row % Tt;
    int tok = tokens[row];
    int i   = d >> 1;
    float ex  = -(float)(2 * i) * (9.210340371976184f / 512.0f);
    float dv  = expf(ex);
    float ang = (float)t * dv;
    float pe  = (d & 1) ? cosf(ang) : sinf(ang);
    x16[idx] = __float2bfloat16(emb[(size_t)tok * D_ + d] + pe);
}

// ---- MFMA bf16 GEMM (unchanged from round 9; see comments there) ----
template <typename CT>
__global__ __launch_bounds__(256) void gemm_mfma(
    const bf16* __restrict__ A, const bf16* __restrict__ Bt,
    const float* __restrict__ bias, CT* __restrict__ C,
    int M, int N, int K, int lt, int relu, int addC, int vt) {
    __shared__ short As[128 * 64];
    __shared__ short Bs[128 * 64];
    int tid  = threadIdx.x;
    int wave = tid >> 6, lane = tid & 63, lr = lane & 15, quad = lane >> 4;
    int wr = (wave >> 1) * 64, wc = (wave & 1) * 64;
    int bx = blockIdx.x, by = blockIdx.y;
    if ((gridDim.y & 7) == 0) {
        int id = by * gridDim.x + bx;
        int xcd = id & 7, slot = id >> 3;
        by = xcd + 8 * (slot / gridDim.x);
        bx = slot % gridDim.x;
    }
    int row0 = by * 128, col0 = bx * 128;
    int srow   = lane >> 3;                    // 0..7 within 8-row segment
    int gchunk = (lane & 7) ^ srow;            // XOR-swizzled source chunk
    f32x4 acc[4][4];
    f32x4 zz = {0.f, 0.f, 0.f, 0.f};
#pragma unroll
    for (int mi = 0; mi < 4; ++mi)
#pragma unroll
        for (int ni = 0; ni < 4; ++ni) acc[mi][ni] = zz;

    int lr7 = lr & 7;
    for (int kt = 0; kt < K; kt += 64) {
#pragma unroll
        for (int sseg = 0; sseg < 4; ++sseg) {
            int s = wave + sseg * 4;           // segment 0..15
            int rloc = s * 8 + srow;
            const bf16* gA = &A[(size_t)(row0 + rloc) * K + kt + gchunk * 8];
            const bf16* gB = &Bt[(size_t)(col0 + rloc) * K + kt + gchunk * 8];
            GLOAD_LDS(gA, &As[s * 512]);
            GLOAD_LDS(gB, &Bs[s * 512]);
        }
        __syncthreads();   // drains vmcnt (async LDS writes) + barrier
#pragma unroll
        for (int ks = 0; ks < 2; ++ks) {
            int cp = (((ks * 4) + quad) ^ lr7) * 8;
            short8 af[4], bf4[4];
#pragma unroll
            for (int mi = 0; mi < 4; ++mi)
                af[mi] = *(const short8*)&As[(wr + mi * 16 + lr) * 64 + cp];
#pragma unroll
            for (int ni = 0; ni < 4; ++ni)
                bf4[ni] = *(const short8*)&Bs[(wc + ni * 16 + lr) * 64 + cp];
#pragma unroll
            for (int mi = 0; mi < 4; ++mi)
#pragma unroll
                for (int ni = 0; ni < 4; ++ni)
                    acc[mi][ni] = __builtin_amdgcn_mfma_f32_16x16x32_bf16(
                        af[mi], bf4[ni], acc[mi][ni], 0, 0, 0);
        }
        __syncthreads();   // protect LDS reuse before next iteration's async writes
    }
    int Ttm1 = (lt >= 0) ? ((1 << lt) - 1) : 0;
#pragma unroll
    for (int ni = 0; ni < 4; ++ni) {
        int gc = col0 + wc + ni * 16 + lr;
        float bi = bias[gc];
#pragma unroll
        for (int mi = 0; mi < 4; ++mi) {
            int gr0 = row0 + wr + mi * 16 + quad * 4;
            f32x4 vv = acc[mi][ni];
#pragma unroll
            for (int rr = 0; rr < 4; ++rr) {
                int r = gr0 + rr;
                float val = vv[rr] + bi;
                if (lt >= 0) {
                    int which = gc >> 9;          // 0=q,1=k,2=v (fused qkv)
                    int h2 = (gc >> 7) & 3, dh = gc & 127;
                    int mq = r >> lt, qi = r & Ttm1;
                    size_t base = (size_t)which * QCHUNK;
                    size_t oi;
                    if (which == 2) oi = base + ((((size_t)(mq * H_ + h2)) * DH_ + dh) << lt) + qi;
                    else            oi = base + ((((size_t)(mq * H_ + h2)) << lt) + qi) * DH_ + dh;
                    storeF(&C[oi], val);
                } else {
                    size_t oi = (size_t)r * N + gc;
                    if (addC) val += toF(C[oi]);
                    if (relu) val = fmaxf(val, 0.f);
                    storeF(&C[oi], val);
                }
            }
        }
    }
}

// ---- MFMA flash attention (unchanged from round 9) ----
__global__ __launch_bounds__(256) void fused_attn(
    const bf16* __restrict__ q, const bf16* __restrict__ k, const bf16* __restrict__ vt,
    bf16* __restrict__ ctx, const int* __restrict__ lens, int Tt, int nqt) {
    __shared__ short Ks[64][136];
    __shared__ short Vs[128][72];
    __shared__ short Ps[4][16][72];
    int bx = blockIdx.x;
    int qt = bx % nqt, mh = bx / nqt;
    int m = mh >> 2, h = mh & 3;
    int tid  = threadIdx.x;
    int wave = tid >> 6, lane = tid & 63, lr = lane & 15, quad = lane >> 4;
    int q0 = qt * 64;
    int kvalid = Tt;
    if (lens) { int l0 = lens[m]; kvalid = l0 < 1 ? 1 : l0; }

    short8 aq[4];
    const bf16* qrow = q + ((size_t)mh * Tt + q0 + wave * 16 + lr) * DH_;
#pragma unroll
    for (int ks2 = 0; ks2 < 4; ++ks2)
        aq[ks2] = *(const short8*)&qrow[ks2 * 32 + quad * 8];

    float mrow[4], lrow[4];
#pragma unroll
    for (int r = 0; r < 4; ++r) { mrow[r] = -INFINITY; lrow[r] = 0.f; }
    f32x4 acco[8];
    f32x4 zz = {0.f, 0.f, 0.f, 0.f};
#pragma unroll
    for (int n = 0; n < 8; ++n) acco[n] = zz;

    int nkt = Tt >> 6;
    for (int kt = 0; kt < nkt; ++kt) {
        int kb = kt * 64;
        __syncthreads();
#pragma unroll
        for (int ee = 0; ee < 4; ++ee) {
            int e = tid + ee * 256;
            int r = e >> 4, c = (e & 15) * 8;
            *(short8*)&Ks[r][c] = *(const short8*)&k[((size_t)mh * Tt + kb + r) * DH_ + c];
        }
#pragma unroll
        for (int ee = 0; ee < 4; ++ee) {
            int e = tid + ee * 256;
            int r = e >> 3, c = (e & 7) * 8;
            *(short8*)&Vs[r][c] = *(const short8*)&vt[((size_t)mh * DH_ + r) * Tt + kb + c];
        }
        __syncthreads();
        f32x4 s[4];
#pragma unroll
        for (int ni = 0; ni < 4; ++ni) s[ni] = zz;
#pragma unroll
        for (int ni = 0; ni < 4; ++ni)
#pragma unroll
            for (int ks2 = 0; ks2 < 4; ++ks2) {
                short8 kf = *(const short8*)&Ks[ni * 16 + lr][ks2 * 32 + quad * 8];
                s[ni] = __builtin_amdgcn_mfma_f32_16x16x32_bf16(aq[ks2], kf, s[ni], 0, 0, 0);
            }
        float mx[4] = {-INFINITY, -INFINITY, -INFINITY, -INFINITY};
#pragma unroll
        for (int ni = 0; ni < 4; ++ni) {
            bool ok = (kb + ni * 16 + lr) < kvalid;
#pragma unroll
            for (int reg = 0; reg < 4; ++reg) {
                float v = s[ni][reg] * 0.08838834764831845f;
                v = ok ? v : -INFINITY;
                s[ni][reg] = v;
                mx[reg] = fmaxf(mx[reg], v);
            }
        }
#pragma unroll
        for (int d2 = 1; d2 < 16; d2 <<= 1)
#pragma unroll
            for (int reg = 0; reg < 4; ++reg)
                mx[reg] = fmaxf(mx[reg], __shfl_xor(mx[reg], d2));
        float alpha[4];
#pragma unroll
        for (int reg = 0; reg < 4; ++reg) {
            float mn = fmaxf(mrow[reg], mx[reg]);
            alpha[reg] = __expf(mrow[reg] - mn);
            mrow[reg] = mn;
        }
        float rs[4] = {0.f, 0.f, 0.f, 0.f};
#pragma unroll
        for (int ni = 0; ni < 4; ++ni)
#pragma unroll
            for (int reg = 0; reg < 4; ++reg) {
                float p = __expf(s[ni][reg] - mrow[reg]);
                s[ni][reg] = p;
                rs[reg] += p;
            }
#pragma unroll
        for (int d2 = 1; d2 < 16; d2 <<= 1)
#pragma unroll
            for (int reg = 0; reg < 4; ++reg)
                rs[reg] += __shfl_xor(rs[reg], d2);
#pragma unroll
        for (int reg = 0; reg < 4; ++reg)
            lrow[reg] = lrow[reg] * alpha[reg] + rs[reg];
#pragma unroll
        for (int ni = 0; ni < 4; ++ni)
#pragma unroll
            for (int reg = 0; reg < 4; ++reg)
                Ps[wave][quad * 4 + reg][ni * 16 + lr] = (short)f2b(s[ni][reg]);
#pragma unroll
        for (int n = 0; n < 8; ++n)
#pragma unroll
            for (int reg = 0; reg < 4; ++reg) acco[n][reg] *= alpha[reg];
#pragma unroll
        for (int ks2 = 0; ks2 < 2; ++ks2) {
            short8 pf = *(const short8*)&Ps[wave][lr][ks2 * 32 + quad * 8];
#pragma unroll
            for (int n = 0; n < 8; ++n) {
                short8 vf = *(const short8*)&Vs[n * 16 + lr][ks2 * 32 + quad * 8];
                acco[n] = __builtin_amdgcn_mfma_f32_16x16x32_bf16(pf, vf, acco[n], 0, 0, 0);
            }
        }
    }
    float linv[4];
#pragma unroll
    for (int reg = 0; reg < 4; ++reg) linv[reg] = 1.f / lrow[reg];
#pragma unroll
    for (int n = 0; n < 8; ++n)
#pragma unroll
        for (int reg = 0; reg < 4; ++reg) {
            int qq = q0 + wave * 16 + quad * 4 + reg;
            ctx[((size_t)m * Tt + qq) * D_ + h * DH_ + n * 16 + lr] =
                __float2bfloat16(acco[n][reg] * linv[reg]);
        }
}

// ---- LayerNorm in place on bf16 (fp32 stats) ----
__global__ void ln_kernel(bf16* __restrict__ x,
                          const float* __restrict__ g,
                          const float* __restrict__ b) {
    int row = blockIdx.x;
    int t   = threadIdx.x;
    __shared__ float red[256];
    float v0 = toF(x[(size_t)row * D_ + t]);
    float v1 = toF(x[(size_t)row * D_ + t + 256]);
    red[t] = v0 + v1;
    __syncthreads();
    for (int off = 128; off > 0; off >>= 1) {
        if (t < off) red[t] += red[t + off];
        __syncthreads();
    }
    float mu = red[0] / 512.f;
    __syncthreads();
    float d0 = v0 - mu, d1 = v1 - mu;
    red[t] = d0 * d0 + d1 * d1;
    __syncthreads();
    for (int off = 128; off > 0; off >>= 1) {
        if (t < off) red[t] += red[t + off];
        __syncthreads();
    }
    float inv = rsqrtf(red[0] / 512.f + 1e-5f);
    x[(size_t)row * D_ + t]       = __float2bfloat16(d0 * inv * g[t] + b[t]);
    x[(size_t)row * D_ + t + 256] = __float2bfloat16(d1 * inv * g[t + 256] + b[t + 256]);
}

__global__ void copy_last_main(const bf16* __restrict__ x, float* __restrict__ bh) {
    int idx = blockIdx.x * blockDim.x + threadIdx.x;  // 64*512
    int b = idx >> 9, d = idx & 511;
    bh[idx] = toF(x[(size_t)(b * S_ + S_ - 1) * D_ + d]);
}

__global__ void add_last_kernel(const bf16* __restrict__ x,
                                const int* __restrict__ lens,
                                float* __restrict__ sep) {
    int idx = blockIdx.x * blockDim.x + threadIdx.x;  // 384*512
    int bn = idx >> 9, d = idx & 511;
    int len = lens[bn];
    float add = (len > 0) ? toF(x[(size_t)(bn * T_ + len - 1) * D_ + d]) : 0.f;
    sep[idx] += add;
}

__global__ void final_kernel(const float* __restrict__ sep,
                             const float* __restrict__ bh,
                             const int* __restrict__ nflag,
                             float* __restrict__ out) {
    int bn = blockIdx.x;
    int b  = bn / NH_;
    int t  = threadIdx.x;  // 256
    __shared__ float red[256];
    float v0 = sep[(size_t)bn * D_ + t];
    float v1 = sep[(size_t)bn * D_ + t + 256];
    int nf = nflag[0];
    float scale = 1.f;
    if (nf) {
        v0 = fmaxf(v0, 0.f);
        v1 = fmaxf(v1, 0.f);
        red[t] = v0 * v0 + v1 * v1;
        __syncthreads();
        for (int off = 128; off > 0; off >>= 1) {
            if (t < off) red[t] += red[t + off];
            __syncthreads();
        }
        scale = 1.f / fmaxf(sqrtf(red[0]), 1e-12f);
        __syncthreads();
    }
    red[t] = v0 * scale * bh[(size_t)b * D_ + t] + v1 * scale * bh[(size_t)b * D_ + t + 256];
    __syncthreads();
    for (int off = 128; off > 0; off >>= 1) {
        if (t < off) red[t] += red[t + off];
        __syncthreads();
    }
    if (t == 0) out[bn] = red[0];
}

extern "C" void kernel_launch(void* const* d_in, const int* in_sizes, int n_in,
                              void* d_out, int out_size, void* d_ws, size_t ws_size,
                              hipStream_t stream) {
    const int*   segment   = (const int*)d_in[0];
    const int*   prev_hist = (const int*)d_in[1];
    const int*   lens      = (const int*)d_in[2];
    const float* sep_img   = (const float*)d_in[3];
    const int*   normalize = (const int*)d_in[4];
    const float* emb       = (const float*)d_in[5];
    const float* Wq = (const float*)d_in[6];
    const float* bq = (const float*)d_in[7];
    const float* Wk = (const float*)d_in[8];
    const float* bk = (const float*)d_in[9];
    const float* Wv = (const float*)d_in[10];
    const float* bv = (const float*)d_in[11];
    const float* Wo = (const float*)d_in[12];
    const float* bo = (const float*)d_in[13];
    const float* ln1g = (const float*)d_in[14];
    const float* ln1b = (const float*)d_in[15];
    const float* W1 = (const float*)d_in[16];
    const float* b1 = (const float*)d_in[17];
    const float* W2 = (const float*)d_in[18];
    const float* b2 = (const float*)d_in[19];
    const float* ln2g = (const float*)d_in[20];
    const float* ln2b = (const float*)d_in[21];
    const float* Wsep = (const float*)d_in[22];
    const float* bsep = (const float*)d_in[23];
    float* out = (float*)d_out;

    // ---- common small buffers + weights ----
    char* w = (char*)d_ws;
    float* bh   = (float*)w; w += (size_t)B_ * D_ * 4;
    float* sepb = (float*)w; w += (size_t)B_ * NH_ * D_ * 4;
    float* bqkv = (float*)w; w += (size_t)L_ * 1536 * 4;
    bf16* Wqkvt = (bf16*)w; w += (size_t)L_ * 1536 * D_ * 2;  // [l][n=1536][k=512]
    bf16* Wot = (bf16*)w; w += (size_t)L_ * D_ * D_ * 2;
    bf16* W1t = (bf16*)w; w += (size_t)L_ * D_ * FF_ * 2;
    bf16* W2t = (bf16*)w; w += (size_t)L_ * FF_ * D_ * 2;
    bf16* Wsept = (bf16*)w; w += (size_t)IMG_ * D_ * 2;

    // combined-path layout needs (bytes from w): x16 + ctx + 3*qkv
    size_t needA = (size_t)NTALL * D_ * 2 * 2 + QCHUNK * 2 * 3;
    bool combined = ((size_t)(w - (char*)d_ws) + needA <= ws_size);

    // ---- weight conversion (identical both paths) ----
    {
        dim3 tg(16, 16, L_);
        size_t qs = (size_t)1536 * D_;
        transpose_cast<<<tg, 256, 0, stream>>>(Wq, Wqkvt,             D_, D_, qs);
        transpose_cast<<<tg, 256, 0, stream>>>(Wk, Wqkvt + 512 * D_,  D_, D_, qs);
        transpose_cast<<<tg, 256, 0, stream>>>(Wv, Wqkvt + 1024 * D_, D_, D_, qs);
        transpose_cast<<<tg, 256, 0, stream>>>(Wo, Wot, D_, D_, (size_t)D_ * D_);
        transpose_cast<<<tg, 256, 0, stream>>>(W1, W1t, D_, FF_, (size_t)D_ * FF_);
        transpose_cast<<<tg, 256, 0, stream>>>(W2, W2t, FF_, D_, (size_t)FF_ * D_);
        transpose_cast<<<dim3(16, 64, 1), 256, 0, stream>>>(Wsep, Wsept, IMG_, D_,
                                                            (size_t)IMG_ * D_);
        gather_qkv_bias<<<(L_ * 1536 + 255) / 256, 256, 0, stream>>>(bq, bk, bv, bqkv);
    }

    if (combined) {
        // ---- combined layout: x16/ctx hold both encoders (40960 rows) ----
        bf16* x16  = (bf16*)w; w += (size_t)NTALL * D_ * 2;
        bf16* ctxb = (bf16*)w; w += (size_t)NTALL * D_ * 2;   // also ffmid
        bf16* qh   = (bf16*)w; w += QCHUNK * 2;               // also sep16 temp
        bf16* kh   = (bf16*)w; w += QCHUNK * 2;
        bf16* vh   = (bf16*)w; w += QCHUNK * 2;
        bf16* x16h  = x16  + (size_t)NTMAIN * D_;
        bf16* ctxh  = ctxb + (size_t)NTMAIN * D_;
        bf16* ffmid = ctxb;
        bf16* sep16 = qh;

        // sep projection first (sep16 lives in qh, dead before first qkv)
        {
            int n = B_ * NH_ * IMG_;
            cast_bf16<<<(n + 255) / 256, 256, 0, stream>>>(sep_img, sep16, n);
            gemm_mfma<float><<<dim3(D_ / 128, (B_ * NH_) / 128), 256, 0, stream>>>(
                sep16, Wsept, bsep, sepb, B_ * NH_, D_, IMG_, -1, 0, 0, 0);
        }
        embed_kernel<<<(NTMAIN * D_) / 256, 256, 0, stream>>>(segment, emb, x16, S_,
                                                              NTMAIN * D_);
        embed_kernel<<<(NTHIST * D_) / 256, 256, 0, stream>>>(prev_hist, emb, x16h, T_,
                                                              NTHIST * D_);
        dim3 ga(D_ / 128, NTALL / 128);          // (4, 320)
        for (int l = 0; l < L_; ++l) {
            size_t wl = (size_t)l * 1536 * D_;
            // main qkv + attention
            gemm_mfma<bf16><<<dim3(12, NTMAIN / 128), 256, 0, stream>>>(
                x16, Wqkvt + wl, bqkv + l * 1536, qh, NTMAIN, 1536, D_, 8, 0, 0, 2);
            fused_attn<<<B_ * H_ * (S_ / 64), 256, 0, stream>>>(
                qh, kh, vh, ctxb, nullptr, S_, S_ / 64);
            // history qkv + attention (stream order guarantees main attn done)
            gemm_mfma<bf16><<<dim3(12, NTHIST / 128), 256, 0, stream>>>(
                x16h, Wqkvt + wl, bqkv + l * 1536, qh, NTHIST, 1536, D_, 6, 0, 0, 2);
            fused_attn<<<B_ * NH_ * H_ * (T_ / 64), 256, 0, stream>>>(
                qh, kh, vh, ctxh, lens, T_, T_ / 64);
            // combined post-attention pipeline over 40960 rows
            gemm_mfma<bf16><<<ga, 256, 0, stream>>>(
                ctxb, Wot + (size_t)l * D_ * D_, bo + l * D_, x16,
                NTALL, D_, D_, -1, 0, 1, 0);  // += resid
            ln_kernel<<<NTALL, 256, 0, stream>>>(x16, ln1g + l * D_, ln1b + l * D_);
            gemm_mfma<bf16><<<ga, 256, 0, stream>>>(
                x16, W1t + (size_t)l * D_ * FF_, b1 + l * FF_, ffmid,
                NTALL, FF_, D_, -1, 1, 0, 0);
            gemm_mfma<bf16><<<ga, 256, 0, stream>>>(
                ffmid, W2t + (size_t)l * FF_ * D_, b2 + l * D_, x16,
                NTALL, D_, FF_, -1, 0, 1, 0); // += resid
            ln_kernel<<<NTALL, 256, 0, stream>>>(x16, ln2g + l * D_, ln2b + l * D_);
        }
        copy_last_main<<<(B_ * D_) / 256, 256, 0, stream>>>(x16, bh);
        add_last_kernel<<<(B_ * NH_ * D_) / 256, 256, 0, stream>>>(x16h, lens, sepb);
        final_kernel<<<B_ * NH_, 256, 0, stream>>>(sepb, bh, normalize, out);
    } else {
        // ---- fallback: round-9 split layout/behavior ----
        bf16* x16  = (bf16*)w; w += QCHUNK * 2;
        bf16* ctxb = (bf16*)w; w += QCHUNK * 2;
        bf16* qh   = (bf16*)w; w += QCHUNK * 2;
        bf16* kh   = (bf16*)w; w += QCHUNK * 2;
        bf16* vh   = (bf16*)w; w += QCHUNK * 2;
        bf16* sep16 = (bf16*)w; w += (size_t)B_ * NH_ * IMG_ * 2;
        bf16* ffmid = qh;

        {
            int n = B_ * NH_ * IMG_;
            cast_bf16<<<(n + 255) / 256, 256, 0, stream>>>(sep_img, sep16, n);
        }
        auto run_encoder = [&](int M, int Tt, int lt, const int* lens_p) {
            int NT = M * Tt;
            dim3 gg(D_ / 128, NT / 128);
            dim3 gq(1536 / 128, NT / 128);
            int nqt = Tt / 64;
            for (int l = 0; l < L_; ++l) {
                gemm_mfma<bf16><<<gq, 256, 0, stream>>>(
                    x16, Wqkvt + (size_t)l * 1536 * D_, bqkv + l * 1536, qh,
                    NT, 1536, D_, lt, 0, 0, 2);
                fused_attn<<<M * H_ * nqt, 256, 0, stream>>>(
                    qh, kh, vh, ctxb, lens_p, Tt, nqt);
                gemm_mfma<bf16><<<gg, 256, 0, stream>>>(
                    ctxb, Wot + (size_t)l * D_ * D_, bo + l * D_, x16,
                    NT, D_, D_, -1, 0, 1, 0);
                ln_kernel<<<NT, 256, 0, stream>>>(x16, ln1g + l * D_, ln1b + l * D_);
                gemm_mfma<bf16><<<gg, 256, 0, stream>>>(
                    x16, W1t + (size_t)l * D_ * FF_, b1 + l * FF_, ffmid,
                    NT, FF_, D_, -1, 1, 0, 0);
                gemm_mfma<bf16><<<gg, 256, 0, stream>>>(
                    ffmid, W2t + (size_t)l * FF_ * D_, b2 + l * D_, x16,
                    NT, D_, FF_, -1, 0, 1, 0);
                ln_kernel<<<NT, 256, 0, stream>>>(x16, ln2g + l * D_, ln2b + l * D_);
            }
        };
        embed_kernel<<<(NTMAIN * D_) / 256, 256, 0, stream>>>(segment, emb, x16, S_,
                                                              NTMAIN * D_);
        run_encoder(B_, S_, 8, nullptr);
        copy_last_main<<<(B_ * D_) / 256, 256, 0, stream>>>(x16, bh);
        gemm_mfma<float><<<dim3(D_ / 128, (B_ * NH_) / 128), 256, 0, stream>>>(
            sep16, Wsept, bsep, sepb, B_ * NH_, D_, IMG_, -1, 0, 0, 0);
        embed_kernel<<<(NTHIST * D_) / 256, 256, 0, stream>>>(prev_hist, emb, x16, T_,
                                                              NTHIST * D_);
        run_encoder(B_ * NH_, T_, 6, lens);
        add_last_kernel<<<(B_ * NH_ * D_) / 256, 256, 0, stream>>>(x16, lens, sepb);
        final_kernel<<<B_ * NH_, 256, 0, stream>>>(sepb, bh, normalize, out);
    }
}